// Round 2
// 570.070 us; speedup vs baseline: 1.0023x; 1.0023x over previous
//
#include <hip/hip_runtime.h>

// TopDownProjector: volume [B=2, C=1, H=512, W=512, D=256] f32, depth innermost.
// Per column: first non-zero scanning from d=255 downward.
//   d_out = [height_field (524288 f32) | seg_map (524288 f32)]
//
// R3 post-mortem: 4B probe == 16B probe (571 vs 569 us) -> kernel is
// line-granule bound, not byte bound. Kernel ~72us vs ~5-10us byte roofline.
// Theory: cost = scattered-lane request handling (64 distinct sectors per
// wave-load) + the "rare" fallback hitting ~100% of WAVES (1-(8/9)^64) with a
// dependent nontemporal re-fetch from DRAM.
//
// R4: coalesced sector probe. 4 lanes x float4 cover the top 16 floats (one
// 64B sector) of each column; cross-lane max-reduce on packed (idx+1|val) key.
// P(column unresolved) = (1/9)^16 ~ 5e-16 -> fallback is correctness-only.
// One load inst per wave = 16 line requests (4x fewer), no dependent chain.
// R5: fix compile error — __builtin_nontemporal_load needs a native vector
// type, not HIP_vector_type. Use clang ext_vector_type(4) float.

#define DDEPTH 256
#define PROBE 16                      // floats probed at top of each column
#define PROBE_BASE (DDEPTH - PROBE)   // 240

typedef float floatx4 __attribute__((ext_vector_type(4)));

__global__ __launch_bounds__(256)
void TopDownProjector_82806969467611_kernel(const float* __restrict__ vol,
                                            float* __restrict__ height,
                                            float* __restrict__ seg,
                                            int ncols) {
    int gid = blockIdx.x * blockDim.x + threadIdx.x;  // one thread per (col, quad)
    int col = gid >> 2;
    int sub = gid & 3;
    if (col >= ncols) return;

    const float* cp = vol + (size_t)col * DDEPTH;

    // Coalesced probe: 4 consecutive lanes read the column's top 64B sector.
    const floatx4* qp = (const floatx4*)(cp + PROBE_BASE);
    floatx4 v = __builtin_nontemporal_load(qp + sub);

    // Highest-index nonzero within this lane's quad (ascending writes: last wins).
    int idx = -1;
    float val = 0.0f;
    if (v.x != 0.0f) { idx = PROBE_BASE + sub * 4 + 0; val = v.x; }
    if (v.y != 0.0f) { idx = PROBE_BASE + sub * 4 + 1; val = v.y; }
    if (v.z != 0.0f) { idx = PROBE_BASE + sub * 4 + 2; val = v.z; }
    if (v.w != 0.0f) { idx = PROBE_BASE + sub * 4 + 3; val = v.w; }

    // Pack (idx+1, val_bits): idx+1 in high word so ull max picks deepest hit.
    // All-empty lanes carry key==0.
    unsigned long long key =
        ((unsigned long long)(unsigned)(idx + 1) << 32) |
        (unsigned long long)__float_as_uint(val);

    // Max-reduce across the 4-lane group (width=4 butterfly).
    unsigned long long o1 = __shfl_xor(key, 1, 4);
    key = key > o1 ? key : o1;
    unsigned long long o2 = __shfl_xor(key, 2, 4);
    key = key > o2 ? key : o2;

    if (sub == 0) {
        int hidx = (int)(key >> 32) - 1;
        float h, s;
        if (hidx >= 0) {
            h = (float)hidx;
            s = __uint_as_float((unsigned)(key & 0xffffffffu));
        } else {
            // Top-16 all zero: prob ~5e-16 per column. Correctness-only path.
            h = 0.0f;
            s = 0.0f;
            for (int d = PROBE_BASE - 1; d >= 0; --d) {
                float x = cp[d];
                if (x != 0.0f) { h = (float)d; s = x; break; }
            }
        }
        // 16 consecutive columns per wave -> stores coalesce into 64B bursts.
        __builtin_nontemporal_store(h, height + col);
        __builtin_nontemporal_store(s, seg + col);
    }
}

extern "C" void kernel_launch(void* const* d_in, const int* in_sizes, int n_in,
                              void* d_out, int out_size, void* d_ws, size_t ws_size,
                              hipStream_t stream) {
    const float* vol = (const float*)d_in[0];
    float* out = (float*)d_out;

    int ncols = in_sizes[0] / DDEPTH;      // 524288
    float* height = out;                   // first output plane
    float* seg    = out + ncols;           // second output plane

    int block = 256;
    long long nthreads = (long long)ncols * 4;   // 4 lanes per column
    int grid = (int)((nthreads + block - 1) / block);
    TopDownProjector_82806969467611_kernel<<<grid, block, 0, stream>>>(
        vol, height, seg, ncols);
}